// Round 19
// baseline (1714.153 us; speedup 1.0000x reference)
//
#include <hip/hip_runtime.h>
#include <cstdint>

typedef __attribute__((ext_vector_type(4))) float f32x4;
typedef __attribute__((ext_vector_type(8))) short short8;
typedef __attribute__((ext_vector_type(4))) short short4v;
typedef _Float16 half8v __attribute__((ext_vector_type(8)));

__device__ __forceinline__ unsigned short f2h(float x) {
  _Float16 h = (_Float16)x;
  return __builtin_bit_cast(unsigned short, h);
}
__device__ __forceinline__ unsigned int pk2(float a, float b) {
  auto h = __builtin_amdgcn_cvt_pkrtz(a, b);
  return __builtin_bit_cast(unsigned int, h);
}

// ---- MFMA wrapper: tolerant of short8-vs-half8 builtin signatures ----
template <typename V>
__device__ __forceinline__ auto mfma_impl(V a, V b, f32x4 c, int)
    -> decltype(__builtin_amdgcn_mfma_f32_16x16x32_f16(a, b, c, 0, 0, 0)) {
  return __builtin_amdgcn_mfma_f32_16x16x32_f16(a, b, c, 0, 0, 0);
}
template <typename V>
__device__ __forceinline__ f32x4 mfma_impl(V a, V b, f32x4 c, long) {
  return __builtin_amdgcn_mfma_f32_16x16x32_f16(
      __builtin_bit_cast(half8v, a), __builtin_bit_cast(half8v, b), c, 0, 0, 0);
}
__device__ __forceinline__ f32x4 MFMA(short8 a, short8 b, f32x4 c) {
  return mfma_impl(a, b, c, 0);
}

// ---- async global->LDS, 16B per lane, LDS dest MUST be wave-uniform ----
__device__ __forceinline__ void load_lds16(const void* g, void* l) {
  __builtin_amdgcn_global_load_lds(
      (__attribute__((address_space(1))) void*)(uintptr_t)g,
      (__attribute__((address_space(3))) void*)l, 16, 0, 0);
}

// ============================ LayerNorm -> f16 =============================
__global__ __launch_bounds__(256) void ln_f16_kernel(
    const float* __restrict__ X, const float* __restrict__ gam,
    const float* __restrict__ bet, unsigned short* __restrict__ Y) {
  __shared__ float red[8];
  const int row = blockIdx.x, t = threadIdx.x;
  const float4 v = ((const float4*)(X + (size_t)row * 1024))[t];
  float s = v.x + v.y + v.z + v.w;
#pragma unroll
  for (int o = 32; o >= 1; o >>= 1) s += __shfl_xor(s, o, 64);
  if ((t & 63) == 0) red[t >> 6] = s;
  __syncthreads();
  const float mean = (red[0] + red[1] + red[2] + red[3]) * (1.0f / 1024.0f);
  const float dx = v.x - mean, dy = v.y - mean, dz = v.z - mean, dw = v.w - mean;
  float ss = dx * dx + dy * dy + dz * dz + dw * dw;
#pragma unroll
  for (int o = 32; o >= 1; o >>= 1) ss += __shfl_xor(ss, o, 64);
  if ((t & 63) == 0) red[4 + (t >> 6)] = ss;
  __syncthreads();
  const float var = (red[4] + red[5] + red[6] + red[7]) * (1.0f / 1024.0f);
  const float rstd = rsqrtf(var + 1e-5f);
  const float4 gg = ((const float4*)gam)[t];
  const float4 bb = ((const float4*)bet)[t];
  ushort4 o4;
  o4.x = f2h(dx * rstd * gg.x + bb.x);
  o4.y = f2h(dy * rstd * gg.y + bb.y);
  o4.z = f2h(dz * rstd * gg.z + bb.z);
  o4.w = f2h(dw * rstd * gg.w + bb.w);
  ((ushort4*)(Y + (size_t)row * 1024))[t] = o4;
}

// ==== batched weight transpose+convert: all 4 matrices of one layer ========
__global__ __launch_bounds__(256) void transpose_all_kernel(
    const float* __restrict__ wq, const float* __restrict__ wo,
    const float* __restrict__ w1, const float* __restrict__ w2,
    unsigned short* __restrict__ wtq, unsigned short* __restrict__ wto,
    unsigned short* __restrict__ wt1, unsigned short* __restrict__ wt2) {
  __shared__ float t[32][33];
  int i = blockIdx.x;
  const float* W; unsigned short* WT; int K, N;
  if (i < 3072)      { W = wq; WT = wtq; K = 1024; N = 3072; }
  else if (i < 4096) { i -= 3072; W = wo; WT = wto; K = 1024; N = 1024; }
  else if (i < 8192) { i -= 4096; W = w1; WT = wt1; K = 1024; N = 4096; }
  else               { i -= 8192; W = w2; WT = wt2; K = 4096; N = 1024; }
  const int nt = N >> 5;
  const int n0 = (i % nt) * 32, k0 = (i / nt) * 32;
  const int tx = threadIdx.x, ty = threadIdx.y;
#pragma unroll
  for (int j = 0; j < 4; ++j)
    t[ty + 8 * j][tx] = W[(size_t)(k0 + ty + 8 * j) * N + n0 + tx];
  __syncthreads();
#pragma unroll
  for (int j = 0; j < 4; ++j)
    WT[(size_t)(n0 + ty + 8 * j) * K + k0 + tx] = f2h(t[tx][ty + 8 * j]);
}

// ============================ GEMM (f16 MFMA) ==============================
// Shape-tuned tiles (r18-proven): BK=64 path swizzle chunk^(row&7); BK=32
// path swizzle chunk^((row>>1)&3). Double-buffered LDS, 2-phase pipeline,
// wave-uniform gload_lds dest with pre-swizzled per-lane source. 1D grid +
// XCD-aware bijective swizzle. EPI 0/3: f16. EPI 1: gelu. EPI 2: f32 res.
// EPI 3: qkv V region (n0>=2048) written transposed into vtout[b][col][row].
template <int BM, int BN, int BK, int EPI>
__global__ __launch_bounds__(256, 4) void gemm_f16_kernel(
    const unsigned short* __restrict__ A, const unsigned short* __restrict__ BT,
    void* Cout, const float* __restrict__ bias, const float* __restrict__ res,
    unsigned short* __restrict__ vtout, int gx, int M, int N, int K) {
  constexpr int MR = BM / 32, NR = BN / 32;
  constexpr int ACH = BM * BK / 8;
  constexpr int BCH = BN * BK / 8;
  __shared__ alignas(16) unsigned short a_sh[2][BM * BK];
  __shared__ alignas(16) unsigned short b_sh[2][BN * BK];
  const int tid = threadIdx.x;
  const int w = tid >> 6, lane = tid & 63, g = lane >> 4, lm = lane & 15;
  int bid = blockIdx.x;
  const int cpx = gridDim.x >> 3;
  bid = (bid & 7) * cpx + (bid >> 3);      // XCD-contiguous tile ids
  const int m0 = (bid / gx) * BM, n0 = (bid % gx) * BN;
  const int wm = (w >> 1) * (BM / 2), wn = (w & 1) * (BN / 2);
  f32x4 acc[MR][NR] = {};
  const int nsteps = K / BK;

  auto stage = [&](int buf, int kk) {
#pragma unroll
    for (int c0 = 0; c0 < ACH; c0 += 256) {
      const int c = c0 + tid;
      int row, sc;
      if (BK == 64) { row = c >> 3; sc = (c & 7) ^ (row & 7); }
      else          { row = c >> 2; sc = (c & 3) ^ ((row >> 1) & 3); }
      const int cb = c0 + (tid & 192);
      load_lds16(A + (size_t)(m0 + row) * K + kk + sc * 8, &a_sh[buf][cb * 8]);
    }
#pragma unroll
    for (int c0 = 0; c0 < BCH; c0 += 256) {
      const int c = c0 + tid;
      int row, sc;
      if (BK == 64) { row = c >> 3; sc = (c & 7) ^ (row & 7); }
      else          { row = c >> 2; sc = (c & 3) ^ ((row >> 1) & 3); }
      const int cb = c0 + (tid & 192);
      load_lds16(BT + (size_t)(n0 + row) * K + kk + sc * 8, &b_sh[buf][cb * 8]);
    }
  };

  stage(0, 0);
  __syncthreads();
  int cur = 0;
  for (int step = 0; step < nsteps; ++step) {
    if (step + 1 < nsteps) stage(cur ^ 1, (step + 1) * BK);
#pragma unroll
    for (int kc = 0; kc < BK / 32; ++kc) {
      short8 af[MR], bfr[NR];
#pragma unroll
      for (int i = 0; i < MR; ++i) {
        const int r = wm + i * 16 + lm;
        const int ko = (BK == 64) ? (((kc << 2) | g) ^ (r & 7))
                                  : (g ^ ((r >> 1) & 3));
        af[i] = *(const short8*)&a_sh[cur][r * BK + ko * 8];
      }
#pragma unroll
      for (int j = 0; j < NR; ++j) {
        const int r = wn + j * 16 + lm;
        const int ko = (BK == 64) ? (((kc << 2) | g) ^ (r & 7))
                                  : (g ^ ((r >> 1) & 3));
        bfr[j] = *(const short8*)&b_sh[cur][r * BK + ko * 8];
      }
#pragma unroll
      for (int i = 0; i < MR; ++i)
#pragma unroll
        for (int j = 0; j < NR; ++j)
          acc[i][j] = MFMA(af[i], bfr[j], acc[i][j]);
    }
    if (step + 1 < nsteps) {
      __syncthreads();
      cur ^= 1;
    }
  }

  if (EPI == 3 && n0 >= 2048) {
#pragma unroll
    for (int i = 0; i < MR; ++i) {
      const int row = m0 + wm + i * 16 + g * 4;
      const int bb = row >> 11, rin = row & 2047;
#pragma unroll
      for (int j = 0; j < NR; ++j) {
        const int vcol = n0 + wn + j * 16 + lm - 2048;
        ushort4 o4;
        o4.x = f2h(acc[i][j][0]);
        o4.y = f2h(acc[i][j][1]);
        o4.z = f2h(acc[i][j][2]);
        o4.w = f2h(acc[i][j][3]);
        *(ushort4*)&vtout[((size_t)bb * 1024 + vcol) * 2048 + rin] = o4;
      }
    }
    return;
  }

#pragma unroll
  for (int i = 0; i < MR; ++i) {
    const int row = m0 + wm + i * 16 + g * 4;
#pragma unroll
    for (int j = 0; j < NR; ++j) {
      const int col = n0 + wn + j * 16 + lm;
#pragma unroll
      for (int r = 0; r < 4; ++r) {
        const float v = acc[i][j][r];
        const size_t idx = (size_t)(row + r) * N + col;
        if (EPI == 0 || EPI == 3) {
          ((unsigned short*)Cout)[idx] = f2h(v);
        } else if (EPI == 1) {
          const float xx = v + bias[col];
          ((unsigned short*)Cout)[idx] =
              f2h(0.5f * xx * (1.0f + erff(xx * 0.70710678118654752f)));
        } else {
          ((float*)Cout)[idx] = res[idx] + v + bias[col];
        }
      }
    }
  }
}

// ============================ Flash attention ==============================
// QBLK=128, 8 waves, grid 512 = 2 blocks/CU. NEW: 128-kv tile staged per
// barrier pair, processed as TWO sequential 64-kv sub-iterations with the
// r13-proven register footprint (sf[4]/p/pbu[2] reused per half). Barriers
// per block: 64 -> 32; longer barrier-to-barrier regions improve the 2-block
// co-residency overlap. LDS 36.3KB (2 blocks/CU unchanged).
__global__ __launch_bounds__(512) void attn_kernel(
    const unsigned short* __restrict__ qkv, const unsigned short* __restrict__ vt,
    unsigned short* __restrict__ obuf) {
  constexpr int PK = 72;    // K row pitch (f16 elems)
  constexpr int PV = 140;   // V^T row pitch: 128 kv + 12 pad (~4-way writes)
  __shared__ alignas(16) unsigned short Ks[128 * PK];
  __shared__ alignas(16) unsigned short VsT[64 * PV];  // VsT[d][kv 0..127]
  const int tid = threadIdx.x;
  const int w = tid >> 6, lane = tid & 63, g = lane >> 4, lm = lane & 15;
  const int qbase = blockIdx.x * 128, h = blockIdx.y, b = blockIdx.z;
  const size_t rowbase = (size_t)b * 2048;
  const int r0 = tid >> 3, cc = tid & 7;  // staging: r0 [0,64), cc [0,8)

  // Q fragments: direct global->reg (one 16B load per half, per lane)
  const unsigned short* qp =
      qkv + (rowbase + qbase + w * 16 + lm) * 3072 + h * 64 + g * 8;
  short8 qf[2];
  qf[0] = *(const short8*)qp;
  qf[1] = *(const short8*)(qp + 32);

  const unsigned short* kptr = qkv + (rowbase + r0) * 3072 + 1024 + h * 64 + cc * 8;
  const unsigned short* vtp = vt + ((size_t)b * 1024 + h * 64 + r0) * 2048 + cc * 8;
  uint4 kreg[2], vreg[2];
  auto load_tile = [&](int n) {
    kreg[0] = *(const uint4*)(kptr + (size_t)n * 128 * 3072);
    kreg[1] = *(const uint4*)(kptr + ((size_t)n * 128 + 64) * 3072);
    vreg[0] = *(const uint4*)(vtp + n * 128);
    vreg[1] = *(const uint4*)(vtp + n * 128 + 64);
  };
  auto write_tile = [&]() {
    *(uint4*)&Ks[r0 * PK + cc * 8] = kreg[0];
    *(uint4*)&Ks[(64 + r0) * PK + cc * 8] = kreg[1];
    *(uint4*)&VsT[r0 * PV + cc * 8] = vreg[0];
    *(uint4*)&VsT[r0 * PV + 64 + cc * 8] = vreg[1];
  };

  load_tile(0);
  float mrun = -1e30f, lrun = 0.0f;
  f32x4 accO[4] = {};

  for (int n = 0; n < 16; ++n) {
    __syncthreads();     // all waves done reading previous tile
    write_tile();
    __syncthreads();     // tile n (128 kv) visible
    if (n + 1 < 16) load_tile(n + 1);  // lands under this iter's compute

#pragma unroll
    for (int half = 0; half < 2; ++half) {
      const int kb = half * 64;

      // S^T = K Q^T (4 kv-subtiles x this wave's 16 q-rows)
      f32x4 sf[4] = {};
      __builtin_amdgcn_s_setprio(1);
#pragma unroll
      for (int s2 = 0; s2 < 2; ++s2)
#pragma unroll
        for (int i = 0; i < 4; ++i) {
          const short8 kf =
              *(const short8*)&Ks[(kb + i * 16 + lm) * PK + s2 * 32 + g * 8];
          sf[i] = MFMA(kf, qf[s2], sf[i]);
        }
      __builtin_amdgcn_s_setprio(0);

      // online softmax per q-row (lanes lm, lm+16, lm+32, lm+48 share a row)
      float tmax = -1e30f;
#pragma unroll
      for (int i = 0; i < 4; ++i)
#pragma unroll
        for (int r = 0; r < 4; ++r) tmax = fmaxf(tmax, sf[i][r]);
      tmax = fmaxf(tmax, __shfl_xor(tmax, 16, 64));
      tmax = fmaxf(tmax, __shfl_xor(tmax, 32, 64));
      const float mnew = fmaxf(mrun, tmax);
      const float scale = __expf(mrun - mnew);
      float p[4][4];
      float psum = 0.0f;
#pragma unroll
      for (int i = 0; i < 4; ++i)
#pragma unroll
        for (int r = 0; r < 4; ++r) {
          p[i][r] = __expf(sf[i][r] - mnew);
          psum += p[i][r];
        }
      psum += __shfl_xor(psum, 16, 64);
      psum += __shfl_xor(psum, 32, 64);
      lrun = lrun * scale + psum;
      mrun = mnew;
#pragma unroll
      for (int t = 0; t < 4; ++t) accO[t] = accO[t] * scale;

      // pack P -> f16 fragments (slot j = p[2blk+(j>>2)][j&3])
      uint4 pbu[2];
#pragma unroll
      for (int blk = 0; blk < 2; ++blk) {
        pbu[blk].x = pk2(p[2 * blk][0], p[2 * blk][1]);
        pbu[blk].y = pk2(p[2 * blk][2], p[2 * blk][3]);
        pbu[blk].z = pk2(p[2 * blk + 1][0], p[2 * blk + 1][1]);
        pbu[blk].w = pk2(p[2 * blk + 1][2], p[2 * blk + 1][3]);
      }

      // O^T += V^T @ P^T ; V fragments via two ds_read_b64 per (blk,t)
      __builtin_amdgcn_s_setprio(1);
#pragma unroll
      for (int blk = 0; blk < 2; ++blk) {
        const short8 pbv = __builtin_bit_cast(short8, pbu[blk]);
#pragma unroll
        for (int t = 0; t < 4; ++t) {
          const int base = (16 * t + lm) * PV + kb + 32 * blk + 4 * g;
          const short4v vlo = *(const short4v*)&VsT[base];
          const short4v vhi = *(const short4v*)&VsT[base + 16];
          const short8 vf = {vlo[0], vlo[1], vlo[2], vlo[3],
                             vhi[0], vhi[1], vhi[2], vhi[3]};
          accO[t] = MFMA(vf, pbv, accO[t]);
        }
      }
      __builtin_amdgcn_s_setprio(0);
    }
  }

  // epilogue: divide by row-sum, multiply by 1/SCALE = 8; vectorized stores
  const float inv = 8.0f / lrun;
  const size_t orow = rowbase + qbase + w * 16 + lm;
#pragma unroll
  for (int t = 0; t < 4; ++t) {
    ushort4 o4;
    o4.x = f2h(accO[t][0] * inv);
    o4.y = f2h(accO[t][1] * inv);
    o4.z = f2h(accO[t][2] * inv);
    o4.w = f2h(accO[t][3] * inv);
    *(ushort4*)&obuf[orow * 1024 + h * 64 + t * 16 + g * 4] = o4;
  }
}

// ================================ driver ===================================
extern "C" void kernel_launch(void* const* d_in, const int* in_sizes, int n_in,
                              void* d_out, int out_size, void* d_ws, size_t ws_size,
                              hipStream_t stream) {
  const float* x     = (const float*)d_in[0];
  const float* ln1_g = (const float*)d_in[1];
  const float* ln1_b = (const float*)d_in[2];
  const float* w_qkv = (const float*)d_in[3];
  const float* w_out = (const float*)d_in[4];
  const float* b_out = (const float*)d_in[5];
  const float* ln2_g = (const float*)d_in[6];
  const float* ln2_b = (const float*)d_in[7];
  const float* w1    = (const float*)d_in[8];
  const float* b1    = (const float*)d_in[9];
  const float* w2    = (const float*)d_in[10];
  const float* b2    = (const float*)d_in[11];
  float* h = (float*)d_out;  // residual stream lives in d_out

  char* ws = (char*)d_ws;
  const size_t MB = 1u << 20;
  unsigned short* xn   = (unsigned short*)(ws);             //  8 MiB (LN out)
  unsigned short* ob   = (unsigned short*)(ws + 8 * MB);    //  8 MiB
  unsigned short* qkvb = (unsigned short*)(ws + 16 * MB);   // 24 MiB
  unsigned short* mid  = (unsigned short*)(ws + 40 * MB);   // 32 MiB (VT or MLP mid)
  unsigned short* wt   = (unsigned short*)(ws + 72 * MB);   // 24 MiB (4 matrices)
  unsigned short* wtq = wt;
  unsigned short* wto = wt + 3145728;
  unsigned short* wt1 = wt + 4194304;
  unsigned short* wt2 = wt + 8388608;

  hipError_t e0 = hipMemcpyAsync(h, x, (size_t)4096 * 1024 * sizeof(float),
                                 hipMemcpyDeviceToDevice, stream);
  (void)e0;

  const dim3 tb(32, 8);
  for (int L = 0; L < 6; ++L) {
    const float* Lg1 = ln1_g + L * 1024;
    const float* Lb1 = ln1_b + L * 1024;
    const float* Lwq = w_qkv + (size_t)L * 1024 * 3072;
    const float* Lwo = w_out + (size_t)L * 1024 * 1024;
    const float* Lbo = b_out + L * 1024;
    const float* Lg2 = ln2_g + L * 1024;
    const float* Lb2 = ln2_b + L * 1024;
    const float* Lw1 = w1 + (size_t)L * 1024 * 4096;
    const float* Lb1m = b1 + L * 4096;
    const float* Lw2 = w2 + (size_t)L * 4096 * 1024;
    const float* Lb2m = b2 + L * 1024;

    transpose_all_kernel<<<12288, tb, 0, stream>>>(
        Lwq, Lwo, Lw1, Lw2, wtq, wto, wt1, wt2);

    // --- attention path ---
    ln_f16_kernel<<<4096, 256, 0, stream>>>(h, Lg1, Lb1, xn);
    gemm_f16_kernel<128, 128, 32, 3><<<768, 256, 0, stream>>>(
        xn, wtq, qkvb, nullptr, nullptr, mid, 24, 4096, 3072, 1024);
    attn_kernel<<<dim3(16, 16, 2), 512, 0, stream>>>(qkvb, mid, ob);
    gemm_f16_kernel<64, 64, 64, 2><<<1024, 256, 0, stream>>>(
        ob, wto, h, Lbo, h, nullptr, 16, 4096, 1024, 1024);

    // --- MLP path ---
    ln_f16_kernel<<<4096, 256, 0, stream>>>(h, Lg2, Lb2, xn);
    gemm_f16_kernel<128, 128, 32, 1><<<1024, 256, 0, stream>>>(
        xn, wt1, mid, Lb1m, nullptr, nullptr, 32, 4096, 4096, 1024);
    gemm_f16_kernel<64, 64, 64, 2><<<1024, 256, 0, stream>>>(
        mid, wt2, h, Lb2m, h, nullptr, 16, 4096, 1024, 4096);
  }
  (void)in_sizes; (void)n_in; (void)out_size; (void)ws_size;
}

// Round 20
// 1494.387 us; speedup vs baseline: 1.1471x; 1.1471x over previous
//
#include <hip/hip_runtime.h>
#include <cstdint>

typedef __attribute__((ext_vector_type(4))) float f32x4;
typedef __attribute__((ext_vector_type(8))) short short8;
typedef __attribute__((ext_vector_type(4))) short short4v;
typedef _Float16 half8v __attribute__((ext_vector_type(8)));

__device__ __forceinline__ unsigned short f2h(float x) {
  _Float16 h = (_Float16)x;
  return __builtin_bit_cast(unsigned short, h);
}
__device__ __forceinline__ unsigned int pk2(float a, float b) {
  auto h = __builtin_amdgcn_cvt_pkrtz(a, b);
  return __builtin_bit_cast(unsigned int, h);
}

// ---- MFMA wrapper: tolerant of short8-vs-half8 builtin signatures ----
template <typename V>
__device__ __forceinline__ auto mfma_impl(V a, V b, f32x4 c, int)
    -> decltype(__builtin_amdgcn_mfma_f32_16x16x32_f16(a, b, c, 0, 0, 0)) {
  return __builtin_amdgcn_mfma_f32_16x16x32_f16(a, b, c, 0, 0, 0);
}
template <typename V>
__device__ __forceinline__ f32x4 mfma_impl(V a, V b, f32x4 c, long) {
  return __builtin_amdgcn_mfma_f32_16x16x32_f16(
      __builtin_bit_cast(half8v, a), __builtin_bit_cast(half8v, b), c, 0, 0, 0);
}
__device__ __forceinline__ f32x4 MFMA(short8 a, short8 b, f32x4 c) {
  return mfma_impl(a, b, c, 0);
}

// ---- async global->LDS, 16B per lane, LDS dest MUST be wave-uniform ----
__device__ __forceinline__ void load_lds16(const void* g, void* l) {
  __builtin_amdgcn_global_load_lds(
      (__attribute__((address_space(1))) void*)(uintptr_t)g,
      (__attribute__((address_space(3))) void*)l, 16, 0, 0);
}

// ============================ LayerNorm -> f16 =============================
__global__ __launch_bounds__(256) void ln_f16_kernel(
    const float* __restrict__ X, const float* __restrict__ gam,
    const float* __restrict__ bet, unsigned short* __restrict__ Y) {
  __shared__ float red[8];
  const int row = blockIdx.x, t = threadIdx.x;
  const float4 v = ((const float4*)(X + (size_t)row * 1024))[t];
  float s = v.x + v.y + v.z + v.w;
#pragma unroll
  for (int o = 32; o >= 1; o >>= 1) s += __shfl_xor(s, o, 64);
  if ((t & 63) == 0) red[t >> 6] = s;
  __syncthreads();
  const float mean = (red[0] + red[1] + red[2] + red[3]) * (1.0f / 1024.0f);
  const float dx = v.x - mean, dy = v.y - mean, dz = v.z - mean, dw = v.w - mean;
  float ss = dx * dx + dy * dy + dz * dz + dw * dw;
#pragma unroll
  for (int o = 32; o >= 1; o >>= 1) ss += __shfl_xor(ss, o, 64);
  if ((t & 63) == 0) red[4 + (t >> 6)] = ss;
  __syncthreads();
  const float var = (red[4] + red[5] + red[6] + red[7]) * (1.0f / 1024.0f);
  const float rstd = rsqrtf(var + 1e-5f);
  const float4 gg = ((const float4*)gam)[t];
  const float4 bb = ((const float4*)bet)[t];
  ushort4 o4;
  o4.x = f2h(dx * rstd * gg.x + bb.x);
  o4.y = f2h(dy * rstd * gg.y + bb.y);
  o4.z = f2h(dz * rstd * gg.z + bb.z);
  o4.w = f2h(dw * rstd * gg.w + bb.w);
  ((ushort4*)(Y + (size_t)row * 1024))[t] = o4;
}

// ==== batched weight transpose+convert: all 4 matrices of one layer ========
__global__ __launch_bounds__(256) void transpose_all_kernel(
    const float* __restrict__ wq, const float* __restrict__ wo,
    const float* __restrict__ w1, const float* __restrict__ w2,
    unsigned short* __restrict__ wtq, unsigned short* __restrict__ wto,
    unsigned short* __restrict__ wt1, unsigned short* __restrict__ wt2) {
  __shared__ float t[32][33];
  int i = blockIdx.x;
  const float* W; unsigned short* WT; int K, N;
  if (i < 3072)      { W = wq; WT = wtq; K = 1024; N = 3072; }
  else if (i < 4096) { i -= 3072; W = wo; WT = wto; K = 1024; N = 1024; }
  else if (i < 8192) { i -= 4096; W = w1; WT = wt1; K = 1024; N = 4096; }
  else               { i -= 8192; W = w2; WT = wt2; K = 4096; N = 1024; }
  const int nt = N >> 5;
  const int n0 = (i % nt) * 32, k0 = (i / nt) * 32;
  const int tx = threadIdx.x, ty = threadIdx.y;
#pragma unroll
  for (int j = 0; j < 4; ++j)
    t[ty + 8 * j][tx] = W[(size_t)(k0 + ty + 8 * j) * N + n0 + tx];
  __syncthreads();
#pragma unroll
  for (int j = 0; j < 4; ++j)
    WT[(size_t)(n0 + ty + 8 * j) * K + k0 + tx] = f2h(t[tx][ty + 8 * j]);
}

// ============================ GEMM (f16 MFMA) ==============================
// Shape-tuned tiles (r18-proven): BK=64 path swizzle chunk^(row&7); BK=32
// path swizzle chunk^((row>>1)&3). Double-buffered LDS, 2-phase pipeline,
// wave-uniform gload_lds dest with pre-swizzled per-lane source. 1D grid +
// XCD-aware bijective swizzle. EPI 0/3: f16. EPI 1: gelu. EPI 2: f32 res.
// EPI 3: qkv V region (n0>=2048) written transposed into vtout[b][col][row].
template <int BM, int BN, int BK, int EPI>
__global__ __launch_bounds__(256, 4) void gemm_f16_kernel(
    const unsigned short* __restrict__ A, const unsigned short* __restrict__ BT,
    void* Cout, const float* __restrict__ bias, const float* __restrict__ res,
    unsigned short* __restrict__ vtout, int gx, int M, int N, int K) {
  constexpr int MR = BM / 32, NR = BN / 32;
  constexpr int ACH = BM * BK / 8;
  constexpr int BCH = BN * BK / 8;
  __shared__ alignas(16) unsigned short a_sh[2][BM * BK];
  __shared__ alignas(16) unsigned short b_sh[2][BN * BK];
  const int tid = threadIdx.x;
  const int w = tid >> 6, lane = tid & 63, g = lane >> 4, lm = lane & 15;
  int bid = blockIdx.x;
  const int cpx = gridDim.x >> 3;
  bid = (bid & 7) * cpx + (bid >> 3);      // XCD-contiguous tile ids
  const int m0 = (bid / gx) * BM, n0 = (bid % gx) * BN;
  const int wm = (w >> 1) * (BM / 2), wn = (w & 1) * (BN / 2);
  f32x4 acc[MR][NR] = {};
  const int nsteps = K / BK;

  auto stage = [&](int buf, int kk) {
#pragma unroll
    for (int c0 = 0; c0 < ACH; c0 += 256) {
      const int c = c0 + tid;
      int row, sc;
      if (BK == 64) { row = c >> 3; sc = (c & 7) ^ (row & 7); }
      else          { row = c >> 2; sc = (c & 3) ^ ((row >> 1) & 3); }
      const int cb = c0 + (tid & 192);
      load_lds16(A + (size_t)(m0 + row) * K + kk + sc * 8, &a_sh[buf][cb * 8]);
    }
#pragma unroll
    for (int c0 = 0; c0 < BCH; c0 += 256) {
      const int c = c0 + tid;
      int row, sc;
      if (BK == 64) { row = c >> 3; sc = (c & 7) ^ (row & 7); }
      else          { row = c >> 2; sc = (c & 3) ^ ((row >> 1) & 3); }
      const int cb = c0 + (tid & 192);
      load_lds16(BT + (size_t)(n0 + row) * K + kk + sc * 8, &b_sh[buf][cb * 8]);
    }
  };

  stage(0, 0);
  __syncthreads();
  int cur = 0;
  for (int step = 0; step < nsteps; ++step) {
    if (step + 1 < nsteps) stage(cur ^ 1, (step + 1) * BK);
#pragma unroll
    for (int kc = 0; kc < BK / 32; ++kc) {
      short8 af[MR], bfr[NR];
#pragma unroll
      for (int i = 0; i < MR; ++i) {
        const int r = wm + i * 16 + lm;
        const int ko = (BK == 64) ? (((kc << 2) | g) ^ (r & 7))
                                  : (g ^ ((r >> 1) & 3));
        af[i] = *(const short8*)&a_sh[cur][r * BK + ko * 8];
      }
#pragma unroll
      for (int j = 0; j < NR; ++j) {
        const int r = wn + j * 16 + lm;
        const int ko = (BK == 64) ? (((kc << 2) | g) ^ (r & 7))
                                  : (g ^ ((r >> 1) & 3));
        bfr[j] = *(const short8*)&b_sh[cur][r * BK + ko * 8];
      }
#pragma unroll
      for (int i = 0; i < MR; ++i)
#pragma unroll
        for (int j = 0; j < NR; ++j)
          acc[i][j] = MFMA(af[i], bfr[j], acc[i][j]);
    }
    if (step + 1 < nsteps) {
      __syncthreads();
      cur ^= 1;
    }
  }

  if (EPI == 3 && n0 >= 2048) {
#pragma unroll
    for (int i = 0; i < MR; ++i) {
      const int row = m0 + wm + i * 16 + g * 4;
      const int bb = row >> 11, rin = row & 2047;
#pragma unroll
      for (int j = 0; j < NR; ++j) {
        const int vcol = n0 + wn + j * 16 + lm - 2048;
        ushort4 o4;
        o4.x = f2h(acc[i][j][0]);
        o4.y = f2h(acc[i][j][1]);
        o4.z = f2h(acc[i][j][2]);
        o4.w = f2h(acc[i][j][3]);
        *(ushort4*)&vtout[((size_t)bb * 1024 + vcol) * 2048 + rin] = o4;
      }
    }
    return;
  }

#pragma unroll
  for (int i = 0; i < MR; ++i) {
    const int row = m0 + wm + i * 16 + g * 4;
#pragma unroll
    for (int j = 0; j < NR; ++j) {
      const int col = n0 + wn + j * 16 + lm;
#pragma unroll
      for (int r = 0; r < 4; ++r) {
        const float v = acc[i][j][r];
        const size_t idx = (size_t)(row + r) * N + col;
        if (EPI == 0 || EPI == 3) {
          ((unsigned short*)Cout)[idx] = f2h(v);
        } else if (EPI == 1) {
          const float xx = v + bias[col];
          ((unsigned short*)Cout)[idx] =
              f2h(0.5f * xx * (1.0f + erff(xx * 0.70710678118654752f)));
        } else {
          ((float*)Cout)[idx] = res[idx] + v + bias[col];
        }
      }
    }
  }
}

// ============================ Flash attention ==============================
// r13/r18-proven optimum (every deviation regressed): QBLK=128 via 8 waves
// (512 threads), grid 512 = 2 blocks/CU. Single-buffer K/V, 2 barriers/iter,
// __expf. Q global->regs. V^T from the fused GEMM epilogue (vt).
__global__ __launch_bounds__(512) void attn_kernel(
    const unsigned short* __restrict__ qkv, const unsigned short* __restrict__ vt,
    unsigned short* __restrict__ obuf) {
  constexpr int PK = 72;   // K row pitch (f16 elems)
  constexpr int PV = 68;   // V^T row pitch: 64 kv + 4 pad
  __shared__ alignas(16) unsigned short Ks[64 * PK];
  __shared__ alignas(16) unsigned short VsT[64 * PV];  // VsT[d][kv]
  const int tid = threadIdx.x;
  const int w = tid >> 6, lane = tid & 63, g = lane >> 4, lm = lane & 15;
  const int qbase = blockIdx.x * 128, h = blockIdx.y, b = blockIdx.z;
  const size_t rowbase = (size_t)b * 2048;
  const int r0 = tid >> 3, cc = tid & 7;  // staging: r0 [0,64), cc [0,8)

  // Q fragments: direct global->reg (one 16B load per half, per lane)
  const unsigned short* qp =
      qkv + (rowbase + qbase + w * 16 + lm) * 3072 + h * 64 + g * 8;
  short8 qf[2];
  qf[0] = *(const short8*)qp;
  qf[1] = *(const short8*)(qp + 32);

  const unsigned short* kptr = qkv + (rowbase + r0) * 3072 + 1024 + h * 64 + cc * 8;
  const unsigned short* vtp = vt + ((size_t)b * 1024 + h * 64 + r0) * 2048 + cc * 8;
  uint4 kreg, vreg;
  auto load_tile = [&](int n) {
    kreg = *(const uint4*)(kptr + (size_t)n * 64 * 3072);
    vreg = *(const uint4*)(vtp + n * 64);
  };
  auto write_tile = [&]() {
    *(uint4*)&Ks[r0 * PK + cc * 8] = kreg;
    *(uint4*)&VsT[r0 * PV + cc * 8] = vreg;
  };

  load_tile(0);
  float mrun = -1e30f, lrun = 0.0f;
  f32x4 accO[4] = {};

  for (int n = 0; n < 32; ++n) {
    __syncthreads();     // all waves done reading previous tile
    write_tile();
    __syncthreads();     // tile n visible
    if (n + 1 < 32) load_tile(n + 1);  // lands under this iter's compute

    // S^T = K Q^T (4 kv-subtiles x this wave's 16 q-rows)
    f32x4 sf[4] = {};
    __builtin_amdgcn_s_setprio(1);
#pragma unroll
    for (int s2 = 0; s2 < 2; ++s2)
#pragma unroll
      for (int i = 0; i < 4; ++i) {
        const short8 kf = *(const short8*)&Ks[(i * 16 + lm) * PK + s2 * 32 + g * 8];
        sf[i] = MFMA(kf, qf[s2], sf[i]);
      }
    __builtin_amdgcn_s_setprio(0);

    // online softmax per q-row (lanes lm, lm+16, lm+32, lm+48 share a row)
    float tmax = -1e30f;
#pragma unroll
    for (int i = 0; i < 4; ++i)
#pragma unroll
      for (int r = 0; r < 4; ++r) tmax = fmaxf(tmax, sf[i][r]);
    tmax = fmaxf(tmax, __shfl_xor(tmax, 16, 64));
    tmax = fmaxf(tmax, __shfl_xor(tmax, 32, 64));
    const float mnew = fmaxf(mrun, tmax);
    const float scale = __expf(mrun - mnew);
    float p[4][4];
    float psum = 0.0f;
#pragma unroll
    for (int i = 0; i < 4; ++i)
#pragma unroll
      for (int r = 0; r < 4; ++r) {
        p[i][r] = __expf(sf[i][r] - mnew);
        psum += p[i][r];
      }
    psum += __shfl_xor(psum, 16, 64);
    psum += __shfl_xor(psum, 32, 64);
    lrun = lrun * scale + psum;
    mrun = mnew;
#pragma unroll
    for (int t = 0; t < 4; ++t) accO[t] = accO[t] * scale;

    // pack P -> f16 fragments (slot j = p[2blk+(j>>2)][j&3])
    uint4 pbu[2];
#pragma unroll
    for (int blk = 0; blk < 2; ++blk) {
      pbu[blk].x = pk2(p[2 * blk][0], p[2 * blk][1]);
      pbu[blk].y = pk2(p[2 * blk][2], p[2 * blk][3]);
      pbu[blk].z = pk2(p[2 * blk + 1][0], p[2 * blk + 1][1]);
      pbu[blk].w = pk2(p[2 * blk + 1][2], p[2 * blk + 1][3]);
    }

    // O^T += V^T @ P^T ; V fragments via two ds_read_b64 per (blk,t)
    __builtin_amdgcn_s_setprio(1);
#pragma unroll
    for (int blk = 0; blk < 2; ++blk) {
      const short8 pbv = __builtin_bit_cast(short8, pbu[blk]);
#pragma unroll
      for (int t = 0; t < 4; ++t) {
        const int base = (16 * t + lm) * PV + 32 * blk + 4 * g;
        const short4v vlo = *(const short4v*)&VsT[base];
        const short4v vhi = *(const short4v*)&VsT[base + 16];
        const short8 vf = {vlo[0], vlo[1], vlo[2], vlo[3],
                           vhi[0], vhi[1], vhi[2], vhi[3]};
        accO[t] = MFMA(vf, pbv, accO[t]);
      }
    }
    __builtin_amdgcn_s_setprio(0);
  }

  // epilogue: divide by row-sum, multiply by 1/SCALE = 8; vectorized stores
  const float inv = 8.0f / lrun;
  const size_t orow = rowbase + qbase + w * 16 + lm;
#pragma unroll
  for (int t = 0; t < 4; ++t) {
    ushort4 o4;
    o4.x = f2h(accO[t][0] * inv);
    o4.y = f2h(accO[t][1] * inv);
    o4.z = f2h(accO[t][2] * inv);
    o4.w = f2h(accO[t][3] * inv);
    *(ushort4*)&obuf[orow * 1024 + h * 64 + t * 16 + g * 4] = o4;
  }
}

// ================================ driver ===================================
extern "C" void kernel_launch(void* const* d_in, const int* in_sizes, int n_in,
                              void* d_out, int out_size, void* d_ws, size_t ws_size,
                              hipStream_t stream) {
  const float* x     = (const float*)d_in[0];
  const float* ln1_g = (const float*)d_in[1];
  const float* ln1_b = (const float*)d_in[2];
  const float* w_qkv = (const float*)d_in[3];
  const float* w_out = (const float*)d_in[4];
  const float* b_out = (const float*)d_in[5];
  const float* ln2_g = (const float*)d_in[6];
  const float* ln2_b = (const float*)d_in[7];
  const float* w1    = (const float*)d_in[8];
  const float* b1    = (const float*)d_in[9];
  const float* w2    = (const float*)d_in[10];
  const float* b2    = (const float*)d_in[11];
  float* h = (float*)d_out;  // residual stream lives in d_out

  char* ws = (char*)d_ws;
  const size_t MB = 1u << 20;
  unsigned short* xn   = (unsigned short*)(ws);             //  8 MiB (LN out)
  unsigned short* ob   = (unsigned short*)(ws + 8 * MB);    //  8 MiB
  unsigned short* qkvb = (unsigned short*)(ws + 16 * MB);   // 24 MiB
  unsigned short* mid  = (unsigned short*)(ws + 40 * MB);   // 32 MiB (VT or MLP mid)
  unsigned short* wt   = (unsigned short*)(ws + 72 * MB);   // 24 MiB (4 matrices)
  unsigned short* wtq = wt;
  unsigned short* wto = wt + 3145728;
  unsigned short* wt1 = wt + 4194304;
  unsigned short* wt2 = wt + 8388608;

  hipError_t e0 = hipMemcpyAsync(h, x, (size_t)4096 * 1024 * sizeof(float),
                                 hipMemcpyDeviceToDevice, stream);
  (void)e0;

  const dim3 tb(32, 8);
  for (int L = 0; L < 6; ++L) {
    const float* Lg1 = ln1_g + L * 1024;
    const float* Lb1 = ln1_b + L * 1024;
    const float* Lwq = w_qkv + (size_t)L * 1024 * 3072;
    const float* Lwo = w_out + (size_t)L * 1024 * 1024;
    const float* Lbo = b_out + L * 1024;
    const float* Lg2 = ln2_g + L * 1024;
    const float* Lb2 = ln2_b + L * 1024;
    const float* Lw1 = w1 + (size_t)L * 1024 * 4096;
    const float* Lb1m = b1 + L * 4096;
    const float* Lw2 = w2 + (size_t)L * 4096 * 1024;
    const float* Lb2m = b2 + L * 1024;

    transpose_all_kernel<<<12288, tb, 0, stream>>>(
        Lwq, Lwo, Lw1, Lw2, wtq, wto, wt1, wt2);

    // --- attention path ---
    ln_f16_kernel<<<4096, 256, 0, stream>>>(h, Lg1, Lb1, xn);
    gemm_f16_kernel<128, 128, 32, 3><<<768, 256, 0, stream>>>(
        xn, wtq, qkvb, nullptr, nullptr, mid, 24, 4096, 3072, 1024);
    attn_kernel<<<dim3(16, 16, 2), 512, 0, stream>>>(qkvb, mid, ob);
    gemm_f16_kernel<64, 64, 64, 2><<<1024, 256, 0, stream>>>(
        ob, wto, h, Lbo, h, nullptr, 16, 4096, 1024, 1024);

    // --- MLP path ---
    ln_f16_kernel<<<4096, 256, 0, stream>>>(h, Lg2, Lb2, xn);
    gemm_f16_kernel<128, 128, 32, 1><<<1024, 256, 0, stream>>>(
        xn, wt1, mid, Lb1m, nullptr, nullptr, 32, 4096, 4096, 1024);
    gemm_f16_kernel<64, 64, 64, 2><<<1024, 256, 0, stream>>>(
        mid, wt2, h, Lb2m, h, nullptr, 16, 4096, 1024, 4096);
  }
  (void)in_sizes; (void)n_in; (void)out_size; (void)ws_size;
}

// Round 21
// 1481.154 us; speedup vs baseline: 1.1573x; 1.0089x over previous
//
#include <hip/hip_runtime.h>
#include <cstdint>

typedef __attribute__((ext_vector_type(4))) float f32x4;
typedef __attribute__((ext_vector_type(8))) short short8;
typedef __attribute__((ext_vector_type(4))) short short4v;
typedef _Float16 half8v __attribute__((ext_vector_type(8)));

__device__ __forceinline__ unsigned short f2h(float x) {
  _Float16 h = (_Float16)x;
  return __builtin_bit_cast(unsigned short, h);
}
__device__ __forceinline__ unsigned int pk2(float a, float b) {
  auto h = __builtin_amdgcn_cvt_pkrtz(a, b);
  return __builtin_bit_cast(unsigned int, h);
}

// ---- MFMA wrapper: tolerant of short8-vs-half8 builtin signatures ----
template <typename V>
__device__ __forceinline__ auto mfma_impl(V a, V b, f32x4 c, int)
    -> decltype(__builtin_amdgcn_mfma_f32_16x16x32_f16(a, b, c, 0, 0, 0)) {
  return __builtin_amdgcn_mfma_f32_16x16x32_f16(a, b, c, 0, 0, 0);
}
template <typename V>
__device__ __forceinline__ f32x4 mfma_impl(V a, V b, f32x4 c, long) {
  return __builtin_amdgcn_mfma_f32_16x16x32_f16(
      __builtin_bit_cast(half8v, a), __builtin_bit_cast(half8v, b), c, 0, 0, 0);
}
__device__ __forceinline__ f32x4 MFMA(short8 a, short8 b, f32x4 c) {
  return mfma_impl(a, b, c, 0);
}

// ---- async global->LDS, 16B per lane, LDS dest MUST be wave-uniform ----
__device__ __forceinline__ void load_lds16(const void* g, void* l) {
  __builtin_amdgcn_global_load_lds(
      (__attribute__((address_space(1))) void*)(uintptr_t)g,
      (__attribute__((address_space(3))) void*)l, 16, 0, 0);
}

// ================== LayerNorm -> f16 (one row per wave, no barriers) ======
__global__ __launch_bounds__(256) void ln_f16_kernel(
    const float* __restrict__ X, const float* __restrict__ gam,
    const float* __restrict__ bet, unsigned short* __restrict__ Y) {
  const int w = threadIdx.x >> 6, lane = threadIdx.x & 63;
  const int row = blockIdx.x * 4 + w;
  const float4* xr = (const float4*)(X + (size_t)row * 1024);
  float4 v[4];
  float s = 0.0f;
#pragma unroll
  for (int i = 0; i < 4; ++i) {
    v[i] = xr[lane + 64 * i];
    s += v[i].x + v[i].y + v[i].z + v[i].w;
  }
#pragma unroll
  for (int o = 32; o >= 1; o >>= 1) s += __shfl_xor(s, o, 64);
  const float mean = s * (1.0f / 1024.0f);
  float ss = 0.0f;
#pragma unroll
  for (int i = 0; i < 4; ++i) {
    v[i].x -= mean; v[i].y -= mean; v[i].z -= mean; v[i].w -= mean;
    ss += v[i].x * v[i].x + v[i].y * v[i].y + v[i].z * v[i].z + v[i].w * v[i].w;
  }
#pragma unroll
  for (int o = 32; o >= 1; o >>= 1) ss += __shfl_xor(ss, o, 64);
  const float rstd = rsqrtf(ss * (1.0f / 1024.0f) + 1e-5f);
#pragma unroll
  for (int i = 0; i < 4; ++i) {
    const float4 gg = ((const float4*)gam)[lane + 64 * i];
    const float4 bb = ((const float4*)bet)[lane + 64 * i];
    ushort4 o4;
    o4.x = f2h(v[i].x * rstd * gg.x + bb.x);
    o4.y = f2h(v[i].y * rstd * gg.y + bb.y);
    o4.z = f2h(v[i].z * rstd * gg.z + bb.z);
    o4.w = f2h(v[i].w * rstd * gg.w + bb.w);
    ((ushort4*)(Y + (size_t)row * 1024))[lane + 64 * i] = o4;
  }
}

// ==== batched weight transpose+convert, vectorized 32x128 tiles ============
// float4 global loads, pk2-packed ushort4 stores. Tile ranges:
//  [0,768): w_qkv ; [768,1024): w_out ; [1024,2048): w1 ; [2048,3072): w2
__global__ __launch_bounds__(256) void transpose_all_kernel(
    const float* __restrict__ wq, const float* __restrict__ wo,
    const float* __restrict__ w1, const float* __restrict__ w2,
    unsigned short* __restrict__ wtq, unsigned short* __restrict__ wto,
    unsigned short* __restrict__ wt1, unsigned short* __restrict__ wt2) {
  __shared__ float t[32 * 132];  // 32 k-rows x 128 n-cols, pitch 132 f32
  int i = blockIdx.x;
  const float* W; unsigned short* WT; int K, N;
  if (i < 768)       {            W = wq; WT = wtq; K = 1024; N = 3072; }
  else if (i < 1024) { i -= 768;  W = wo; WT = wto; K = 1024; N = 1024; }
  else if (i < 2048) { i -= 1024; W = w1; WT = wt1; K = 1024; N = 4096; }
  else               { i -= 2048; W = w2; WT = wt2; K = 4096; N = 1024; }
  const int nt = N >> 7;
  const int n0 = (i % nt) * 128, k0 = (i / nt) * 32;
  const int tid = threadIdx.x;
#pragma unroll
  for (int q = 0; q < 4; ++q) {
    const int idx = q * 256 + tid;          // [0,1024) float4 chunks
    const int r = idx >> 5, c4 = idx & 31;
    const float4 v = *(const float4*)&W[(size_t)(k0 + r) * N + n0 + c4 * 4];
    *(float4*)&t[r * 132 + c4 * 4] = v;
  }
  __syncthreads();
#pragma unroll
  for (int q = 0; q < 4; ++q) {
    const int idx = q * 256 + tid;          // [0,1024) ushort4 chunks
    const int n = idx >> 3, kc = idx & 7;
    const float a = t[(kc * 4 + 0) * 132 + n];
    const float b = t[(kc * 4 + 1) * 132 + n];
    const float c = t[(kc * 4 + 2) * 132 + n];
    const float d = t[(kc * 4 + 3) * 132 + n];
    const unsigned lo = pk2(a, b), hi = pk2(c, d);
    ushort4 o4;
    o4.x = (unsigned short)(lo & 0xffffu); o4.y = (unsigned short)(lo >> 16);
    o4.z = (unsigned short)(hi & 0xffffu); o4.w = (unsigned short)(hi >> 16);
    *(ushort4*)&WT[(size_t)(n0 + n) * K + k0 + kc * 4] = o4;
  }
}

// ============================ GEMM (f16 MFMA) ==============================
// Shape-tuned tiles (r18-proven): BK=64 path swizzle chunk^(row&7); BK=32
// path swizzle chunk^((row>>1)&3). Double-buffered LDS, 2-phase pipeline,
// wave-uniform gload_lds dest with pre-swizzled per-lane source. 1D grid +
// XCD-aware bijective swizzle. EPI 0/3: f16. EPI 1: gelu. EPI 2: f32 res.
// EPI 3: qkv V region (n0>=2048) written transposed into vtout[b][col][row].
template <int BM, int BN, int BK, int EPI>
__global__ __launch_bounds__(256, 4) void gemm_f16_kernel(
    const unsigned short* __restrict__ A, const unsigned short* __restrict__ BT,
    void* Cout, const float* __restrict__ bias, const float* __restrict__ res,
    unsigned short* __restrict__ vtout, int gx, int M, int N, int K) {
  constexpr int MR = BM / 32, NR = BN / 32;
  constexpr int ACH = BM * BK / 8;
  constexpr int BCH = BN * BK / 8;
  __shared__ alignas(16) unsigned short a_sh[2][BM * BK];
  __shared__ alignas(16) unsigned short b_sh[2][BN * BK];
  const int tid = threadIdx.x;
  const int w = tid >> 6, lane = tid & 63, g = lane >> 4, lm = lane & 15;
  int bid = blockIdx.x;
  const int cpx = gridDim.x >> 3;
  bid = (bid & 7) * cpx + (bid >> 3);      // XCD-contiguous tile ids
  const int m0 = (bid / gx) * BM, n0 = (bid % gx) * BN;
  const int wm = (w >> 1) * (BM / 2), wn = (w & 1) * (BN / 2);
  f32x4 acc[MR][NR] = {};
  const int nsteps = K / BK;

  auto stage = [&](int buf, int kk) {
#pragma unroll
    for (int c0 = 0; c0 < ACH; c0 += 256) {
      const int c = c0 + tid;
      int row, sc;
      if (BK == 64) { row = c >> 3; sc = (c & 7) ^ (row & 7); }
      else          { row = c >> 2; sc = (c & 3) ^ ((row >> 1) & 3); }
      const int cb = c0 + (tid & 192);
      load_lds16(A + (size_t)(m0 + row) * K + kk + sc * 8, &a_sh[buf][cb * 8]);
    }
#pragma unroll
    for (int c0 = 0; c0 < BCH; c0 += 256) {
      const int c = c0 + tid;
      int row, sc;
      if (BK == 64) { row = c >> 3; sc = (c & 7) ^ (row & 7); }
      else          { row = c >> 2; sc = (c & 3) ^ ((row >> 1) & 3); }
      const int cb = c0 + (tid & 192);
      load_lds16(BT + (size_t)(n0 + row) * K + kk + sc * 8, &b_sh[buf][cb * 8]);
    }
  };

  stage(0, 0);
  __syncthreads();
  int cur = 0;
  for (int step = 0; step < nsteps; ++step) {
    if (step + 1 < nsteps) stage(cur ^ 1, (step + 1) * BK);
#pragma unroll
    for (int kc = 0; kc < BK / 32; ++kc) {
      short8 af[MR], bfr[NR];
#pragma unroll
      for (int i = 0; i < MR; ++i) {
        const int r = wm + i * 16 + lm;
        const int ko = (BK == 64) ? (((kc << 2) | g) ^ (r & 7))
                                  : (g ^ ((r >> 1) & 3));
        af[i] = *(const short8*)&a_sh[cur][r * BK + ko * 8];
      }
#pragma unroll
      for (int j = 0; j < NR; ++j) {
        const int r = wn + j * 16 + lm;
        const int ko = (BK == 64) ? (((kc << 2) | g) ^ (r & 7))
                                  : (g ^ ((r >> 1) & 3));
        bfr[j] = *(const short8*)&b_sh[cur][r * BK + ko * 8];
      }
#pragma unroll
      for (int i = 0; i < MR; ++i)
#pragma unroll
        for (int j = 0; j < NR; ++j)
          acc[i][j] = MFMA(af[i], bfr[j], acc[i][j]);
    }
    if (step + 1 < nsteps) {
      __syncthreads();
      cur ^= 1;
    }
  }

  if (EPI == 3 && n0 >= 2048) {
#pragma unroll
    for (int i = 0; i < MR; ++i) {
      const int row = m0 + wm + i * 16 + g * 4;
      const int bb = row >> 11, rin = row & 2047;
#pragma unroll
      for (int j = 0; j < NR; ++j) {
        const int vcol = n0 + wn + j * 16 + lm - 2048;
        ushort4 o4;
        o4.x = f2h(acc[i][j][0]);
        o4.y = f2h(acc[i][j][1]);
        o4.z = f2h(acc[i][j][2]);
        o4.w = f2h(acc[i][j][3]);
        *(ushort4*)&vtout[((size_t)bb * 1024 + vcol) * 2048 + rin] = o4;
      }
    }
    return;
  }

#pragma unroll
  for (int i = 0; i < MR; ++i) {
    const int row = m0 + wm + i * 16 + g * 4;
#pragma unroll
    for (int j = 0; j < NR; ++j) {
      const int col = n0 + wn + j * 16 + lm;
#pragma unroll
      for (int r = 0; r < 4; ++r) {
        const float v = acc[i][j][r];
        const size_t idx = (size_t)(row + r) * N + col;
        if (EPI == 0 || EPI == 3) {
          ((unsigned short*)Cout)[idx] = f2h(v);
        } else if (EPI == 1) {
          const float xx = v + bias[col];
          ((unsigned short*)Cout)[idx] =
              f2h(0.5f * xx * (1.0f + erff(xx * 0.70710678118654752f)));
        } else {
          ((float*)Cout)[idx] = res[idx] + v + bias[col];
        }
      }
    }
  }
}

// ============================ Flash attention ==============================
// r13/r18-proven optimum (every deviation regressed): QBLK=128 via 8 waves
// (512 threads), grid 512 = 2 blocks/CU. Single-buffer K/V, 2 barriers/iter,
// __expf. Q global->regs. V^T from the fused GEMM epilogue (vt).
__global__ __launch_bounds__(512) void attn_kernel(
    const unsigned short* __restrict__ qkv, const unsigned short* __restrict__ vt,
    unsigned short* __restrict__ obuf) {
  constexpr int PK = 72;   // K row pitch (f16 elems)
  constexpr int PV = 68;   // V^T row pitch: 64 kv + 4 pad
  __shared__ alignas(16) unsigned short Ks[64 * PK];
  __shared__ alignas(16) unsigned short VsT[64 * PV];  // VsT[d][kv]
  const int tid = threadIdx.x;
  const int w = tid >> 6, lane = tid & 63, g = lane >> 4, lm = lane & 15;
  const int qbase = blockIdx.x * 128, h = blockIdx.y, b = blockIdx.z;
  const size_t rowbase = (size_t)b * 2048;
  const int r0 = tid >> 3, cc = tid & 7;  // staging: r0 [0,64), cc [0,8)

  // Q fragments: direct global->reg (one 16B load per half, per lane)
  const unsigned short* qp =
      qkv + (rowbase + qbase + w * 16 + lm) * 3072 + h * 64 + g * 8;
  short8 qf[2];
  qf[0] = *(const short8*)qp;
  qf[1] = *(const short8*)(qp + 32);

  const unsigned short* kptr = qkv + (rowbase + r0) * 3072 + 1024 + h * 64 + cc * 8;
  const unsigned short* vtp = vt + ((size_t)b * 1024 + h * 64 + r0) * 2048 + cc * 8;
  uint4 kreg, vreg;
  auto load_tile = [&](int n) {
    kreg = *(const uint4*)(kptr + (size_t)n * 64 * 3072);
    vreg = *(const uint4*)(vtp + n * 64);
  };
  auto write_tile = [&]() {
    *(uint4*)&Ks[r0 * PK + cc * 8] = kreg;
    *(uint4*)&VsT[r0 * PV + cc * 8] = vreg;
  };

  load_tile(0);
  float mrun = -1e30f, lrun = 0.0f;
  f32x4 accO[4] = {};

  for (int n = 0; n < 32; ++n) {
    __syncthreads();     // all waves done reading previous tile
    write_tile();
    __syncthreads();     // tile n visible
    if (n + 1 < 32) load_tile(n + 1);  // lands under this iter's compute

    // S^T = K Q^T (4 kv-subtiles x this wave's 16 q-rows)
    f32x4 sf[4] = {};
    __builtin_amdgcn_s_setprio(1);
#pragma unroll
    for (int s2 = 0; s2 < 2; ++s2)
#pragma unroll
      for (int i = 0; i < 4; ++i) {
        const short8 kf = *(const short8*)&Ks[(i * 16 + lm) * PK + s2 * 32 + g * 8];
        sf[i] = MFMA(kf, qf[s2], sf[i]);
      }
    __builtin_amdgcn_s_setprio(0);

    // online softmax per q-row (lanes lm, lm+16, lm+32, lm+48 share a row)
    float tmax = -1e30f;
#pragma unroll
    for (int i = 0; i < 4; ++i)
#pragma unroll
      for (int r = 0; r < 4; ++r) tmax = fmaxf(tmax, sf[i][r]);
    tmax = fmaxf(tmax, __shfl_xor(tmax, 16, 64));
    tmax = fmaxf(tmax, __shfl_xor(tmax, 32, 64));
    const float mnew = fmaxf(mrun, tmax);
    const float scale = __expf(mrun - mnew);
    float p[4][4];
    float psum = 0.0f;
#pragma unroll
    for (int i = 0; i < 4; ++i)
#pragma unroll
      for (int r = 0; r < 4; ++r) {
        p[i][r] = __expf(sf[i][r] - mnew);
        psum += p[i][r];
      }
    psum += __shfl_xor(psum, 16, 64);
    psum += __shfl_xor(psum, 32, 64);
    lrun = lrun * scale + psum;
    mrun = mnew;
#pragma unroll
    for (int t = 0; t < 4; ++t) accO[t] = accO[t] * scale;

    // pack P -> f16 fragments (slot j = p[2blk+(j>>2)][j&3])
    uint4 pbu[2];
#pragma unroll
    for (int blk = 0; blk < 2; ++blk) {
      pbu[blk].x = pk2(p[2 * blk][0], p[2 * blk][1]);
      pbu[blk].y = pk2(p[2 * blk][2], p[2 * blk][3]);
      pbu[blk].z = pk2(p[2 * blk + 1][0], p[2 * blk + 1][1]);
      pbu[blk].w = pk2(p[2 * blk + 1][2], p[2 * blk + 1][3]);
    }

    // O^T += V^T @ P^T ; V fragments via two ds_read_b64 per (blk,t)
    __builtin_amdgcn_s_setprio(1);
#pragma unroll
    for (int blk = 0; blk < 2; ++blk) {
      const short8 pbv = __builtin_bit_cast(short8, pbu[blk]);
#pragma unroll
      for (int t = 0; t < 4; ++t) {
        const int base = (16 * t + lm) * PV + 32 * blk + 4 * g;
        const short4v vlo = *(const short4v*)&VsT[base];
        const short4v vhi = *(const short4v*)&VsT[base + 16];
        const short8 vf = {vlo[0], vlo[1], vlo[2], vlo[3],
                           vhi[0], vhi[1], vhi[2], vhi[3]};
        accO[t] = MFMA(vf, pbv, accO[t]);
      }
    }
    __builtin_amdgcn_s_setprio(0);
  }

  // epilogue: divide by row-sum, multiply by 1/SCALE = 8; vectorized stores
  const float inv = 8.0f / lrun;
  const size_t orow = rowbase + qbase + w * 16 + lm;
#pragma unroll
  for (int t = 0; t < 4; ++t) {
    ushort4 o4;
    o4.x = f2h(accO[t][0] * inv);
    o4.y = f2h(accO[t][1] * inv);
    o4.z = f2h(accO[t][2] * inv);
    o4.w = f2h(accO[t][3] * inv);
    *(ushort4*)&obuf[orow * 1024 + h * 64 + t * 16 + g * 4] = o4;
  }
}

// ================================ driver ===================================
extern "C" void kernel_launch(void* const* d_in, const int* in_sizes, int n_in,
                              void* d_out, int out_size, void* d_ws, size_t ws_size,
                              hipStream_t stream) {
  const float* x     = (const float*)d_in[0];
  const float* ln1_g = (const float*)d_in[1];
  const float* ln1_b = (const float*)d_in[2];
  const float* w_qkv = (const float*)d_in[3];
  const float* w_out = (const float*)d_in[4];
  const float* b_out = (const float*)d_in[5];
  const float* ln2_g = (const float*)d_in[6];
  const float* ln2_b = (const float*)d_in[7];
  const float* w1    = (const float*)d_in[8];
  const float* b1    = (const float*)d_in[9];
  const float* w2    = (const float*)d_in[10];
  const float* b2    = (const float*)d_in[11];
  float* h = (float*)d_out;  // residual stream lives in d_out

  char* ws = (char*)d_ws;
  const size_t MB = 1u << 20;
  unsigned short* xn   = (unsigned short*)(ws);             //  8 MiB (LN out)
  unsigned short* ob   = (unsigned short*)(ws + 8 * MB);    //  8 MiB
  unsigned short* qkvb = (unsigned short*)(ws + 16 * MB);   // 24 MiB
  unsigned short* mid  = (unsigned short*)(ws + 40 * MB);   // 32 MiB (VT or MLP mid)
  unsigned short* wt   = (unsigned short*)(ws + 72 * MB);   // 24 MiB (4 matrices)
  unsigned short* wtq = wt;
  unsigned short* wto = wt + 3145728;
  unsigned short* wt1 = wt + 4194304;
  unsigned short* wt2 = wt + 8388608;

  hipError_t e0 = hipMemcpyAsync(h, x, (size_t)4096 * 1024 * sizeof(float),
                                 hipMemcpyDeviceToDevice, stream);
  (void)e0;

  for (int L = 0; L < 6; ++L) {
    const float* Lg1 = ln1_g + L * 1024;
    const float* Lb1 = ln1_b + L * 1024;
    const float* Lwq = w_qkv + (size_t)L * 1024 * 3072;
    const float* Lwo = w_out + (size_t)L * 1024 * 1024;
    const float* Lbo = b_out + L * 1024;
    const float* Lg2 = ln2_g + L * 1024;
    const float* Lb2 = ln2_b + L * 1024;
    const float* Lw1 = w1 + (size_t)L * 1024 * 4096;
    const float* Lb1m = b1 + L * 4096;
    const float* Lw2 = w2 + (size_t)L * 4096 * 1024;
    const float* Lb2m = b2 + L * 1024;

    transpose_all_kernel<<<3072, 256, 0, stream>>>(
        Lwq, Lwo, Lw1, Lw2, wtq, wto, wt1, wt2);

    // --- attention path ---
    ln_f16_kernel<<<1024, 256, 0, stream>>>(h, Lg1, Lb1, xn);
    gemm_f16_kernel<128, 128, 32, 3><<<768, 256, 0, stream>>>(
        xn, wtq, qkvb, nullptr, nullptr, mid, 24, 4096, 3072, 1024);
    attn_kernel<<<dim3(16, 16, 2), 512, 0, stream>>>(qkvb, mid, ob);
    gemm_f16_kernel<64, 64, 64, 2><<<1024, 256, 0, stream>>>(
        ob, wto, h, Lbo, h, nullptr, 16, 4096, 1024, 1024);

    // --- MLP path ---
    ln_f16_kernel<<<1024, 256, 0, stream>>>(h, Lg2, Lb2, xn);
    gemm_f16_kernel<128, 128, 32, 1><<<1024, 256, 0, stream>>>(
        xn, wt1, mid, Lb1m, nullptr, nullptr, 32, 4096, 4096, 1024);
    gemm_f16_kernel<64, 64, 64, 2><<<1024, 256, 0, stream>>>(
        mid, wt2, h, Lb2m, h, nullptr, 16, 4096, 1024, 4096);
  }
  (void)in_sizes; (void)n_in; (void)out_size; (void)ws_size;
}